// Round 11
// baseline (2411.003 us; speedup 1.0000x reference)
//
#include <hip/hip_runtime.h>
#include <hip/hip_bf16.h>

typedef unsigned short u16;
typedef __attribute__((ext_vector_type(8))) short short8;
typedef __attribute__((ext_vector_type(4))) float f32x4;

#define BATCH_ 32

static __device__ __forceinline__ float b2f(u16 u) {
  union { unsigned int i; float f; } v; v.i = ((unsigned int)u) << 16; return v.f;
}
static __device__ __forceinline__ u16 f2b(float x) {
  unsigned int i = __float_as_uint(x);
  unsigned int r = (i + 0x7fffu + ((i >> 16) & 1u)) >> 16;
  return (u16)r;
}

#define GCAST(p) ((const __attribute__((address_space(1))) void*)(p))
#define LCAST(p) ((__attribute__((address_space(3))) void*)(p))

// ---- elementwise f32 -> bf16 (n % 4 == 0)
__global__ __launch_bounds__(256) void cvt_bf16(const float* __restrict__ src,
                                                u16* __restrict__ dst, int n) {
  int i = (blockIdx.x * 256 + threadIdx.x) * 4;
  if (i >= n) return;
  float4 v = *(const float4*)(src + i);
  ushort4 o;
  o.x = f2b(v.x); o.y = f2b(v.y); o.z = f2b(v.z); o.w = f2b(v.w);
  *(ushort4*)(dst + i) = o;
}

// ---- transpose f32 [R][C] -> bf16 [C][R]
__global__ __launch_bounds__(256) void transpose_cvt(const float* __restrict__ src,
                                                     u16* __restrict__ dst, int R, int C) {
  __shared__ float tile[32][33];
  int c0 = blockIdx.x * 32, r0 = blockIdx.y * 32;
  int tx = threadIdx.x & 31, ty = threadIdx.x >> 5;
  #pragma unroll
  for (int i = 0; i < 32; i += 8)
    tile[ty + i][tx] = src[(long long)(r0 + ty + i) * C + c0 + tx];
  __syncthreads();
  #pragma unroll
  for (int i = 0; i < 32; i += 8)
    dst[(long long)(c0 + ty + i) * R + r0 + tx] = f2b(tile[tx][ty + i]);
}

// ---- scaled[b][k][o] = otherT[k][o] * fix[b][o]   (bf16)
__global__ __launch_bounds__(256) void build_scaled(const u16* __restrict__ oT,
                                                    const float* __restrict__ fix,
                                                    u16* __restrict__ out) {
  long long i4 = (long long)blockIdx.x * 256 + threadIdx.x; // group of 4 along o
  int o = (int)(i4 & 511) * 4;
  long long bk = i4 >> 9;            // b*512 + kk
  int b = (int)(bk >> 9);
  int kk = (int)(bk & 511);
  ushort4 v = *(const ushort4*)(oT + (long long)kk * 2048 + o);
  float4 f = *(const float4*)(fix + (long long)b * 2048 + o);
  ushort4 r;
  r.x = f2b(b2f(v.x) * f.x); r.y = f2b(b2f(v.y) * f.y);
  r.z = f2b(b2f(v.z) * f.z); r.w = f2b(b2f(v.w) * f.w);
  *(ushort4*)(out + bk * 2048 + o) = r;
}

// ---- masked row softmax: P[row][:] = softmax(S[row][:] * 1/sqrt(512), mask)
__global__ __launch_bounds__(256) void softmax_mask(const float* __restrict__ S,
                                                    const int* __restrict__ mask,
                                                    u16* __restrict__ P, int N) {
  const float scale = 0.044194173824159216f; // 1/sqrt(512)
  int row = blockIdx.x;
  int t = threadIdx.x;
  long long base = (long long)row * N;
  float vals[8]; int msk[8];
  float mx = -3.0e38f;
  #pragma unroll
  for (int i = 0; i < 8; ++i) {
    int c = t + i * 256;
    float s = S[base + c] * scale;
    int m = mask[base + c];
    vals[i] = s; msk[i] = m;
    if (!m) mx = fmaxf(mx, s);
  }
  #pragma unroll
  for (int off = 32; off; off >>= 1) mx = fmaxf(mx, __shfl_xor(mx, off));
  __shared__ float sred[4];
  if ((t & 63) == 0) sred[t >> 6] = mx;
  __syncthreads();
  mx = fmaxf(fmaxf(sred[0], sred[1]), fmaxf(sred[2], sred[3]));
  __syncthreads();
  float e[8]; float sum = 0.f;
  #pragma unroll
  for (int i = 0; i < 8; ++i) {
    e[i] = msk[i] ? 0.f : __expf(vals[i] - mx);
    sum += e[i];
  }
  #pragma unroll
  for (int off = 32; off; off >>= 1) sum += __shfl_xor(sum, off);
  if ((t & 63) == 0) sred[t >> 6] = sum;
  __syncthreads();
  sum = sred[0] + sred[1] + sred[2] + sred[3];
  float inv = (sum > 0.f) ? (1.f / sum) : 0.f;
  #pragma unroll
  for (int i = 0; i < 8; ++i) {
    int c = t + i * 256;
    P[base + c] = f2b(e[i] * inv);
  }
}

// ========== r2-proven 128x128 / BK=32 GEMM (small GEMMs: Q|K proj, S) ======
#define GBM 128
#define GBN 128
#define GBK 32

template<int EPI>
__global__ __launch_bounds__(256) void gemm_lds(
    const u16* __restrict__ A, const u16* __restrict__ Bt,
    const float* __restrict__ bias,
    const u16* __restrict__ Bt2, const float* __restrict__ bias2,
    float* __restrict__ outF, u16* __restrict__ outB,
    int M, int N, int K) {
  __shared__ u16 sA[GBM * GBK];
  __shared__ u16 sB[GBN * GBK];
  int m0 = blockIdx.y * GBM, n0 = blockIdx.x * GBN;
  if (EPI == 0) {
    if (2 * blockIdx.y >= gridDim.y) { Bt = Bt2; bias = bias2; }
  }
  int t = threadIdx.x;
  int wid = t >> 6, lane = t & 63;
  int wm = (wid >> 1) * 64, wn = (wid & 1) * 64;
  int lr = lane & 15, lq = lane >> 4;
  int srow = lane >> 2, schunk = (lane & 3) * 8;

  f32x4 acc[4][4];
  #pragma unroll
  for (int i = 0; i < 4; ++i)
    #pragma unroll
    for (int j = 0; j < 4; ++j)
      acc[i][j] = (f32x4){0.f, 0.f, 0.f, 0.f};

  const u16* gA = A + (long long)(m0 + wid * 32 + srow) * K + schunk;
  const u16* gB = Bt + (long long)(n0 + wid * 32 + srow) * K + schunk;
  u16* lA = &sA[(wid * 32) * GBK];
  u16* lB = &sB[(wid * 32) * GBK];
  const long long rowskip = (long long)16 * K;

  for (int k0 = 0; k0 < K; k0 += GBK) {
    __builtin_amdgcn_global_load_lds(GCAST(gA + k0),           LCAST(lA),            16, 0, 0);
    __builtin_amdgcn_global_load_lds(GCAST(gA + k0 + rowskip), LCAST(lA + 16 * GBK), 16, 0, 0);
    __builtin_amdgcn_global_load_lds(GCAST(gB + k0),           LCAST(lB),            16, 0, 0);
    __builtin_amdgcn_global_load_lds(GCAST(gB + k0 + rowskip), LCAST(lB + 16 * GBK), 16, 0, 0);
    __syncthreads();
    short8 af[4], bf[4];
    #pragma unroll
    for (int i = 0; i < 4; ++i)
      af[i] = *(const short8*)&sA[(wm + i * 16 + lr) * GBK + lq * 8];
    #pragma unroll
    for (int j = 0; j < 4; ++j)
      bf[j] = *(const short8*)&sB[(wn + j * 16 + lr) * GBK + lq * 8];
    #pragma unroll
    for (int i = 0; i < 4; ++i)
      #pragma unroll
      for (int j = 0; j < 4; ++j)
        acc[i][j] = __builtin_amdgcn_mfma_f32_16x16x32_bf16(af[i], bf[j], acc[i][j], 0, 0, 0);
    __syncthreads();
  }

  #pragma unroll
  for (int i = 0; i < 4; ++i) {
    #pragma unroll
    for (int j = 0; j < 4; ++j) {
      int col = n0 + wn + j * 16 + lr;
      #pragma unroll
      for (int r = 0; r < 4; ++r) {
        int row = m0 + wm + i * 16 + lq * 4 + r;
        float v = acc[i][j][r];
        if (EPI == 0) {
          outB[(long long)row * N + col] = f2b(v + bias[col]);
        } else {
          outF[(long long)row * N + col] = v;
        }
      }
    }
  }
}

// ========== ring-2 256x256 GEMM, 64KB LDS -> 2 blocks/CU (cross-block =====
// overlap, m114/m97 mechanism). R7-proven components: 16x16x32 MFMA, zero-
// conflict swizzle, SGB interleave, reg frag prefetch.
// Iter kt: RD next-tile frags from buf[(kt+1)&1]; STAGE tile kt+2 into
// buf[kt&1] (tile kt's reads lgkm-drained at end of iter kt-1); 32 MFMA;
// lgkmcnt(0)+vmcnt(0) (stage is ~1242cy old, L2-resident => free); barrier.
// Two unsynchronized blocks per CU interleave read phases with MFMA phases.
#define SGB __builtin_amdgcn_sched_group_barrier
// masks: MFMA=0x008, VMEM_READ=0x020, DS_READ=0x100

__global__ __launch_bounds__(512, 4) void gemm_ring(
    const u16* __restrict__ A, const u16* __restrict__ Bt,
    float* __restrict__ outF, int M, int N, int K) {
  __shared__ u16 lds[2][2][8192];   // [buf][A/B][row*32 + slot*8] = 64 KiB

  // XCD-chunked swizzle: XCD owns contiguous N-chunk, M fastest inside.
  int nwg = gridDim.x * gridDim.y;
  int wg = blockIdx.y * gridDim.x + blockIdx.x;
  int cpx = nwg >> 3;
  int swz = (wg & 7) * cpx + (wg >> 3);
  int bx = swz & 7, by = swz >> 3;          // gridDim.x == 8
  int m0 = bx * 256, n0 = by * 256;

  int t = threadIdx.x;
  int w = t >> 6, lane = t & 63;
  int wr = w >> 2, wc = w & 3;              // wave tile: 128 rows x 64 cols
  int lr = lane & 15, lq = lane >> 4;
  int csw = (((lr >> 1) & 3) ^ lq) * 8;     // swizzled slot offset (u16), 2-way

  // staging source (pre-swizzled): thread t covers row (t>>2), slot (t&3)
  int srow = t >> 2;                                  // 0..127
  int sgc = (((srow >> 1) & 3) ^ (t & 3)) * 8;        // inverse-swizzled chunk
  const u16* pA0 = A + (long long)(m0 + srow) * K + sgc;
  const u16* pA1 = pA0 + (long long)128 * K;
  const u16* pB0 = Bt + (long long)(n0 + srow) * K + sgc;
  const u16* pB1 = pB0 + (long long)128 * K;
  const int lbase = (w * 16) * 32;           // wave-uniform LDS base (u16)

  f32x4 acc[8][4];
  #pragma unroll
  for (int i = 0; i < 8; ++i)
    #pragma unroll
    for (int j = 0; j < 4; ++j)
      acc[i][j] = (f32x4){0.f, 0.f, 0.f, 0.f};

  const int NT = K >> 5;   // K/32 tiles (=64, even)

  #define STAGE_TILE(KT, SB_)                                                         \
    do {                                                                              \
      long long cofs = (long long)(KT) * 32;                                          \
      __builtin_amdgcn_global_load_lds(GCAST(pA0 + cofs), LCAST(&lds[SB_][0][lbase]),            16, 0, 0); \
      __builtin_amdgcn_global_load_lds(GCAST(pA1 + cofs), LCAST(&lds[SB_][0][lbase + 128 * 32]), 16, 0, 0); \
      __builtin_amdgcn_global_load_lds(GCAST(pB0 + cofs), LCAST(&lds[SB_][1][lbase]),            16, 0, 0); \
      __builtin_amdgcn_global_load_lds(GCAST(pB1 + cofs), LCAST(&lds[SB_][1][lbase + 128 * 32]), 16, 0, 0); \
    } while (0)

  #define RD_FRAGS(AF, BF, BUF) {                                                     \
    _Pragma("unroll")                                                                 \
    for (int i = 0; i < 8; ++i)                                                       \
      AF[i] = *(const short8*)&lds[BUF][0][(wr * 128 + i * 16 + lr) * 32 + csw];      \
    _Pragma("unroll")                                                                 \
    for (int j = 0; j < 4; ++j)                                                       \
      BF[j] = *(const short8*)&lds[BUF][1][(wc * 64 + j * 16 + lr) * 32 + csw]; }

  #define MFMA_NP(AF, BF) {                                                           \
    _Pragma("unroll")                                                                 \
    for (int i = 0; i < 8; ++i)                                                       \
      _Pragma("unroll")                                                               \
      for (int j = 0; j < 4; ++j)                                                     \
        acc[i][j] = __builtin_amdgcn_mfma_f32_16x16x32_bf16(AF[i], BF[j], acc[i][j], 0, 0, 0); }

  // issue-interleave: MFMA2 | {DS2 MFMA4}x3 | VMEM4 | {DS2 MFMA4}x3 | MFMA6
  #define SGB_TAIL() {                                                                \
    SGB(0x008, 2, 0);                                                                 \
    SGB(0x100, 2, 0); SGB(0x008, 4, 0);                                               \
    SGB(0x100, 2, 0); SGB(0x008, 4, 0);                                               \
    SGB(0x100, 2, 0); SGB(0x008, 4, 0);                                               \
    SGB(0x020, 4, 0);                                                                 \
    SGB(0x100, 2, 0); SGB(0x008, 4, 0);                                               \
    SGB(0x100, 2, 0); SGB(0x008, 4, 0);                                               \
    SGB(0x100, 2, 0); SGB(0x008, 4, 0);                                               \
    SGB(0x008, 6, 0); }

  #define IT_SYNC() do {                                                              \
    __builtin_amdgcn_sched_barrier(0);                                                \
    asm volatile("s_waitcnt vmcnt(0) lgkmcnt(0)" ::: "memory");                       \
    __builtin_amdgcn_s_barrier();                                                     \
    __builtin_amdgcn_sched_barrier(0);                                                \
  } while (0)

  short8 afA[8], bfA[4], afB[8], bfB[4];

  // prologue: stage tiles 0,1; drain; barrier; read tile 0 into regs
  STAGE_TILE(0, 0);
  STAGE_TILE(1, 1);
  asm volatile("s_waitcnt vmcnt(0)" ::: "memory");
  __builtin_amdgcn_s_barrier();
  __builtin_amdgcn_sched_barrier(0);
  RD_FRAGS(afA, bfA, 0);                     // regs <- tile 0
  asm volatile("s_waitcnt lgkmcnt(0)" ::: "memory");  // protect vs STAGE(2)->buf0
  __builtin_amdgcn_sched_barrier(0);

  // steady: 2 iters/body. Invariant at iter kt: tile kt in regs, tile kt+1
  // resident in buf[(kt+1)&1], buf[kt&1] free to overwrite (reads drained).
  for (int kt = 0; kt + 2 < NT; kt += 2) {
    // ---- iter kt (cur = A)
    RD_FRAGS(afB, bfB, 1);                   // tile kt+1 (resident)
    STAGE_TILE(kt + 2, 0);                   // overwrite tile kt's buffer
    MFMA_NP(afA, bfA);                       // tile kt
    SGB_TAIL();
    IT_SYNC();
    // ---- iter kt+1 (cur = B)
    RD_FRAGS(afA, bfA, 0);                   // tile kt+2
    STAGE_TILE(kt + 3, 1);                   // kt+3 <= NT-1 always in this loop
    MFMA_NP(afB, bfB);
    SGB_TAIL();
    IT_SYNC();
  }

  // tail: tiles NT-2 (in regs afA), NT-1 (in buf1)
  RD_FRAGS(afB, bfB, 1);                     // tile NT-1
  __builtin_amdgcn_sched_barrier(0);
  __builtin_amdgcn_s_setprio(1);
  MFMA_NP(afA, bfA);                         // tile NT-2
  __builtin_amdgcn_s_setprio(0);
  __builtin_amdgcn_sched_barrier(0);
  asm volatile("s_waitcnt lgkmcnt(0)" ::: "memory");
  __builtin_amdgcn_s_setprio(1);
  MFMA_NP(afB, bfB);                         // tile NT-1
  __builtin_amdgcn_s_setprio(0);

  #undef STAGE_TILE
  #undef RD_FRAGS
  #undef MFMA_NP
  #undef SGB_TAIL
  #undef IT_SYNC

  // epilogue: scatter cols -> per-batch layout
  #pragma unroll
  for (int i = 0; i < 8; ++i) {
    #pragma unroll
    for (int j = 0; j < 4; ++j) {
      int col = n0 + wc * 64 + j * 16 + lr;
      int b = col >> 9, kc = col & 511;
      float* ob = outF + (long long)b * ((long long)M * 512) + kc;
      #pragma unroll
      for (int r = 0; r < 4; ++r) {
        int row = m0 + wr * 128 + i * 16 + lq * 4 + r;
        ob[(long long)row * 512] = acc[i][j][r];
      }
    }
  }
}

// ============ fallback (round-1 kernel) for small-ws path ============
#define BMT 128
#define BNT 128
#define BKT 32
#define LDSP 40

template<int MODE>
__global__ __launch_bounds__(256) void gemm_bt(
    const u16* __restrict__ A, const u16* __restrict__ Bt,
    const float* __restrict__ bias, const float* __restrict__ fixmat,
    float* __restrict__ outF, u16* __restrict__ outB,
    int M, int N, int K, long long out_batch_stride, int bt_batch_stride) {
  __shared__ u16 sA[BMT][LDSP];
  __shared__ u16 sB[BNT][LDSP];
  int b = blockIdx.z;
  const u16* Bt_b = Bt + (long long)b * bt_batch_stride;
  const float* fixrow = (MODE == 2) ? (fixmat + (long long)b * K) : nullptr;
  float* out_b = (MODE != 0) ? (outF + (long long)b * out_batch_stride) : nullptr;

  int m0 = blockIdx.y * BMT, n0 = blockIdx.x * BNT;
  int t = threadIdx.x;
  int wid = t >> 6, lane = t & 63;
  int wm = (wid >> 1) * 64, wn = (wid & 1) * 64;
  int lr = lane & 15, lq = lane >> 4;

  f32x4 acc[4][4];
  #pragma unroll
  for (int i = 0; i < 4; ++i)
    #pragma unroll
    for (int j = 0; j < 4; ++j)
      acc[i][j] = (f32x4){0.f, 0.f, 0.f, 0.f};

  int srow = t >> 1, scg = (t & 1) * 16;

  for (int k0 = 0; k0 < K; k0 += BKT) {
    {
      const u16* src = A + (long long)(m0 + srow) * K + k0 + scg;
      short8 v0 = *(const short8*)(src);
      short8 v1 = *(const short8*)(src + 8);
      *(short8*)&sA[srow][scg] = v0;
      *(short8*)&sA[srow][scg + 8] = v1;
    }
    {
      const u16* src = Bt_b + (long long)(n0 + srow) * K + k0 + scg;
      short8 v0 = *(const short8*)(src);
      short8 v1 = *(const short8*)(src + 8);
      if (MODE == 2) {
        u16* p0 = (u16*)&v0; u16* p1 = (u16*)&v1;
        #pragma unroll
        for (int j = 0; j < 8; ++j) {
          p0[j] = f2b(b2f(p0[j]) * fixrow[k0 + scg + j]);
          p1[j] = f2b(b2f(p1[j]) * fixrow[k0 + scg + 8 + j]);
        }
      }
      *(short8*)&sB[srow][scg] = v0;
      *(short8*)&sB[srow][scg + 8] = v1;
    }
    __syncthreads();
    short8 af[4], bf[4];
    #pragma unroll
    for (int i = 0; i < 4; ++i)
      af[i] = *(const short8*)&sA[wm + i * 16 + lr][lq * 8];
    #pragma unroll
    for (int j = 0; j < 4; ++j)
      bf[j] = *(const short8*)&sB[wn + j * 16 + lr][lq * 8];
    #pragma unroll
    for (int i = 0; i < 4; ++i)
      #pragma unroll
      for (int j = 0; j < 4; ++j)
        acc[i][j] = __builtin_amdgcn_mfma_f32_16x16x32_bf16(af[i], bf[j], acc[i][j], 0, 0, 0);
    __syncthreads();
  }

  #pragma unroll
  for (int i = 0; i < 4; ++i) {
    #pragma unroll
    for (int j = 0; j < 4; ++j) {
      int col = n0 + wn + j * 16 + lr;
      #pragma unroll
      for (int r = 0; r < 4; ++r) {
        int row = m0 + wm + i * 16 + lq * 4 + r;
        float v = acc[i][j][r];
        if (MODE == 0) {
          v += bias[col];
          outB[(long long)row * N + col] = f2b(v);
        } else {
          out_b[(long long)row * N + col] = v;
        }
      }
    }
  }
}

extern "C" void kernel_launch(void* const* d_in, const int* in_sizes, int n_in,
                              void* d_out, int out_size, void* d_ws, size_t ws_size,
                              hipStream_t stream) {
  const float* main_feat  = (const float*)d_in[0];
  const float* other_feat = (const float*)d_in[1];
  const float* fix_feat   = (const float*)d_in[2];
  const int*   mask       = (const int*)d_in[3];
  const float* Wq         = (const float*)d_in[4];
  const float* bq         = (const float*)d_in[5];
  const float* Wk         = (const float*)d_in[6];
  const float* bk         = (const float*)d_in[7];
  float* out = (float*)d_out;

  char* ws = (char*)d_ws;
  const size_t OFF_MAINB  = 0;
  const size_t OFF_OTHERB = 2097152;
  const size_t OFF_WQB    = 4194304;
  const size_t OFF_WKB    = 4718592;
  const size_t OFF_QB     = 5242880;
  const size_t OFF_KB     = 7340032;
  const size_t OFF_OTB    = 9437184;
  const size_t OFF_P      = 11534336;
  const size_t OFF_S      = 19922944;
  const size_t OFF_SCALED = 36700160;
  const size_t NEED_SCALED = OFF_SCALED + (size_t)BATCH_ * 512 * 2048 * 2;

  u16* mainB  = (u16*)(ws + OFF_MAINB);
  u16* otherB = (u16*)(ws + OFF_OTHERB);
  u16* WqB    = (u16*)(ws + OFF_WQB);
  u16* WkB    = (u16*)(ws + OFF_WKB);
  u16* QB     = (u16*)(ws + OFF_QB);
  u16* KB     = (u16*)(ws + OFF_KB);
  u16* oTB    = (u16*)(ws + OFF_OTB);
  u16* P      = (u16*)(ws + OFF_P);
  float* S    = (float*)(ws + OFF_S);
  u16* scaled = (u16*)(ws + OFF_SCALED);
  bool use_scaled = (ws_size >= NEED_SCALED);

  // 1) bf16 conversions
  cvt_bf16<<<1024, 256, 0, stream>>>(main_feat, mainB, 2048 * 512);
  cvt_bf16<<<1024, 256, 0, stream>>>(other_feat, otherB, 2048 * 512);
  cvt_bf16<<<256, 256, 0, stream>>>(Wq, WqB, 512 * 512);
  cvt_bf16<<<256, 256, 0, stream>>>(Wk, WkB, 512 * 512);
  // 2) otherT bf16 [512][2048]
  transpose_cvt<<<dim3(16, 64), 256, 0, stream>>>(other_feat, oTB, 2048, 512);

  if (use_scaled) {
    // 3) fused Q|K projection
    gemm_lds<0><<<dim3(4, 32), 256, 0, stream>>>(mainB, WqB, bq, WkB, bk,
        nullptr, QB, 4096, 512, 512);
    // 4) S = Q @ K^T
    gemm_lds<1><<<dim3(16, 16), 256, 0, stream>>>(QB, KB, nullptr, nullptr, nullptr,
        S, nullptr, 2048, 2048, 512);
    // 5) masked softmax -> P bf16
    softmax_mask<<<2048, 256, 0, stream>>>(S, mask, P, 2048);
    // 6) scaled as Bt [16384][2048]
    build_scaled<<<32768, 256, 0, stream>>>(oTB, fix_feat, scaled);
    // 7) ring-2 pipelined GEMM (2 blocks/CU): out[b][m][k] via col scatter
    gemm_ring<<<dim3(8, 64), 512, 0, stream>>>(P, scaled, out, 2048, 16384, 2048);
  } else {
    gemm_bt<0><<<dim3(4, 16, 1), 256, 0, stream>>>(mainB, WqB, bq, nullptr,
        nullptr, QB, 2048, 512, 512, 0, 0);
    gemm_bt<0><<<dim3(4, 16, 1), 256, 0, stream>>>(otherB, WkB, bk, nullptr,
        nullptr, KB, 2048, 512, 512, 0, 0);
    gemm_bt<1><<<dim3(16, 16, 1), 256, 0, stream>>>(QB, KB, nullptr, nullptr,
        S, nullptr, 2048, 2048, 512, 0, 0);
    softmax_mask<<<2048, 256, 0, stream>>>(S, mask, P, 2048);
    gemm_bt<2><<<dim3(4, 16, BATCH_), 256, 0, stream>>>(P, oTB, nullptr, fix_feat,
        out, nullptr, 2048, 512, 2048, 1048576LL, 0);
  }
}

// Round 12
// 422.375 us; speedup vs baseline: 5.7082x; 5.7082x over previous
//
#include <hip/hip_runtime.h>
#include <hip/hip_bf16.h>

typedef unsigned short u16;
typedef __attribute__((ext_vector_type(8))) short short8;
typedef __attribute__((ext_vector_type(4))) float f32x4;

#define BATCH_ 32

static __device__ __forceinline__ float b2f(u16 u) {
  union { unsigned int i; float f; } v; v.i = ((unsigned int)u) << 16; return v.f;
}
static __device__ __forceinline__ u16 f2b(float x) {
  unsigned int i = __float_as_uint(x);
  unsigned int r = (i + 0x7fffu + ((i >> 16) & 1u)) >> 16;
  return (u16)r;
}

#define GCAST(p) ((const __attribute__((address_space(1))) void*)(p))
#define LCAST(p) ((__attribute__((address_space(3))) void*)(p))

// ---- elementwise f32 -> bf16 (n % 4 == 0)
__global__ __launch_bounds__(256) void cvt_bf16(const float* __restrict__ src,
                                                u16* __restrict__ dst, int n) {
  int i = (blockIdx.x * 256 + threadIdx.x) * 4;
  if (i >= n) return;
  float4 v = *(const float4*)(src + i);
  ushort4 o;
  o.x = f2b(v.x); o.y = f2b(v.y); o.z = f2b(v.z); o.w = f2b(v.w);
  *(ushort4*)(dst + i) = o;
}

// ---- transpose f32 [R][C] -> bf16 [C][R]
__global__ __launch_bounds__(256) void transpose_cvt(const float* __restrict__ src,
                                                     u16* __restrict__ dst, int R, int C) {
  __shared__ float tile[32][33];
  int c0 = blockIdx.x * 32, r0 = blockIdx.y * 32;
  int tx = threadIdx.x & 31, ty = threadIdx.x >> 5;
  #pragma unroll
  for (int i = 0; i < 32; i += 8)
    tile[ty + i][tx] = src[(long long)(r0 + ty + i) * C + c0 + tx];
  __syncthreads();
  #pragma unroll
  for (int i = 0; i < 32; i += 8)
    dst[(long long)(c0 + ty + i) * R + r0 + tx] = f2b(tile[tx][ty + i]);
}

// ---- scaled[b][k][o] = otherT[k][o] * fix[b][o]   (bf16)
__global__ __launch_bounds__(256) void build_scaled(const u16* __restrict__ oT,
                                                    const float* __restrict__ fix,
                                                    u16* __restrict__ out) {
  long long i4 = (long long)blockIdx.x * 256 + threadIdx.x; // group of 4 along o
  int o = (int)(i4 & 511) * 4;
  long long bk = i4 >> 9;            // b*512 + kk
  int b = (int)(bk >> 9);
  int kk = (int)(bk & 511);
  ushort4 v = *(const ushort4*)(oT + (long long)kk * 2048 + o);
  float4 f = *(const float4*)(fix + (long long)b * 2048 + o);
  ushort4 r;
  r.x = f2b(b2f(v.x) * f.x); r.y = f2b(b2f(v.y) * f.y);
  r.z = f2b(b2f(v.z) * f.z); r.w = f2b(b2f(v.w) * f.w);
  *(ushort4*)(out + bk * 2048 + o) = r;
}

// ---- masked row softmax: P[row][:] = softmax(S[row][:] * 1/sqrt(512), mask)
__global__ __launch_bounds__(256) void softmax_mask(const float* __restrict__ S,
                                                    const int* __restrict__ mask,
                                                    u16* __restrict__ P, int N) {
  const float scale = 0.044194173824159216f; // 1/sqrt(512)
  int row = blockIdx.x;
  int t = threadIdx.x;
  long long base = (long long)row * N;
  float vals[8]; int msk[8];
  float mx = -3.0e38f;
  #pragma unroll
  for (int i = 0; i < 8; ++i) {
    int c = t + i * 256;
    float s = S[base + c] * scale;
    int m = mask[base + c];
    vals[i] = s; msk[i] = m;
    if (!m) mx = fmaxf(mx, s);
  }
  #pragma unroll
  for (int off = 32; off; off >>= 1) mx = fmaxf(mx, __shfl_xor(mx, off));
  __shared__ float sred[4];
  if ((t & 63) == 0) sred[t >> 6] = mx;
  __syncthreads();
  mx = fmaxf(fmaxf(sred[0], sred[1]), fmaxf(sred[2], sred[3]));
  __syncthreads();
  float e[8]; float sum = 0.f;
  #pragma unroll
  for (int i = 0; i < 8; ++i) {
    e[i] = msk[i] ? 0.f : __expf(vals[i] - mx);
    sum += e[i];
  }
  #pragma unroll
  for (int off = 32; off; off >>= 1) sum += __shfl_xor(sum, off);
  if ((t & 63) == 0) sred[t >> 6] = sum;
  __syncthreads();
  sum = sred[0] + sred[1] + sred[2] + sred[3];
  float inv = (sum > 0.f) ? (1.f / sum) : 0.f;
  #pragma unroll
  for (int i = 0; i < 8; ++i) {
    int c = t + i * 256;
    P[base + c] = f2b(e[i] * inv);
  }
}

// ========== r2-proven 128x128 / BK=32 GEMM (small GEMMs: Q|K proj, S) ======
#define GBM 128
#define GBN 128
#define GBK 32

template<int EPI>
__global__ __launch_bounds__(256) void gemm_lds(
    const u16* __restrict__ A, const u16* __restrict__ Bt,
    const float* __restrict__ bias,
    const u16* __restrict__ Bt2, const float* __restrict__ bias2,
    float* __restrict__ outF, u16* __restrict__ outB,
    int M, int N, int K) {
  __shared__ u16 sA[GBM * GBK];
  __shared__ u16 sB[GBN * GBK];
  int m0 = blockIdx.y * GBM, n0 = blockIdx.x * GBN;
  if (EPI == 0) {
    if (2 * blockIdx.y >= gridDim.y) { Bt = Bt2; bias = bias2; }
  }
  int t = threadIdx.x;
  int wid = t >> 6, lane = t & 63;
  int wm = (wid >> 1) * 64, wn = (wid & 1) * 64;
  int lr = lane & 15, lq = lane >> 4;
  int srow = lane >> 2, schunk = (lane & 3) * 8;

  f32x4 acc[4][4];
  #pragma unroll
  for (int i = 0; i < 4; ++i)
    #pragma unroll
    for (int j = 0; j < 4; ++j)
      acc[i][j] = (f32x4){0.f, 0.f, 0.f, 0.f};

  const u16* gA = A + (long long)(m0 + wid * 32 + srow) * K + schunk;
  const u16* gB = Bt + (long long)(n0 + wid * 32 + srow) * K + schunk;
  u16* lA = &sA[(wid * 32) * GBK];
  u16* lB = &sB[(wid * 32) * GBK];
  const long long rowskip = (long long)16 * K;

  for (int k0 = 0; k0 < K; k0 += GBK) {
    __builtin_amdgcn_global_load_lds(GCAST(gA + k0),           LCAST(lA),            16, 0, 0);
    __builtin_amdgcn_global_load_lds(GCAST(gA + k0 + rowskip), LCAST(lA + 16 * GBK), 16, 0, 0);
    __builtin_amdgcn_global_load_lds(GCAST(gB + k0),           LCAST(lB),            16, 0, 0);
    __builtin_amdgcn_global_load_lds(GCAST(gB + k0 + rowskip), LCAST(lB + 16 * GBK), 16, 0, 0);
    __syncthreads();
    short8 af[4], bf[4];
    #pragma unroll
    for (int i = 0; i < 4; ++i)
      af[i] = *(const short8*)&sA[(wm + i * 16 + lr) * GBK + lq * 8];
    #pragma unroll
    for (int j = 0; j < 4; ++j)
      bf[j] = *(const short8*)&sB[(wn + j * 16 + lr) * GBK + lq * 8];
    #pragma unroll
    for (int i = 0; i < 4; ++i)
      #pragma unroll
      for (int j = 0; j < 4; ++j)
        acc[i][j] = __builtin_amdgcn_mfma_f32_16x16x32_bf16(af[i], bf[j], acc[i][j], 0, 0, 0);
    __syncthreads();
  }

  #pragma unroll
  for (int i = 0; i < 4; ++i) {
    #pragma unroll
    for (int j = 0; j < 4; ++j) {
      int col = n0 + wn + j * 16 + lr;
      #pragma unroll
      for (int r = 0; r < 4; ++r) {
        int row = m0 + wm + i * 16 + lq * 4 + r;
        float v = acc[i][j][r];
        if (EPI == 0) {
          outB[(long long)row * N + col] = f2b(v + bias[col]);
        } else {
          outF[(long long)row * N + col] = v;
        }
      }
    }
  }
}

// ========== LDS-free direct GEMM: 256x256 tile, frags straight from L2 =====
// C[m][n] = sum_k A[m][k]*Bt[n][k]; epilogue scatter n -> (b=n>>9, k=n&511).
// 512 thr = 8 waves (2M x 4N), wave tile 128x64, 16x16x32 MFMA.
// NO LDS, NO barriers: each lane loads its own MFMA fragments directly from
// global (A-panel 1MB / B-panel 1MB are L2-resident; each dwordx4 covers 16
// full 64B lines). Waves run free -> one wave's VMEM overlaps another's MFMA
// (m114). Double-buffered frag regs = prefetch depth 1 iter (~640cy >> L2
// latency); compiler inserts counted vmcnt from the register dependence.
// K hardcoded 2048 (row stride) so offsets are 32-bit and fold to constants.
#define KBIG 2048

__global__ __launch_bounds__(512, 2) void gemm_direct(
    const u16* __restrict__ A, const u16* __restrict__ Bt,
    float* __restrict__ outF, int M, int N) {
  // XCD-chunked swizzle: XCD owns contiguous N-chunk, M fastest inside.
  int nwg = gridDim.x * gridDim.y;
  int wg = blockIdx.y * gridDim.x + blockIdx.x;
  int cpx = nwg >> 3;
  int swz = (wg & 7) * cpx + (wg >> 3);
  int bx = swz & 7, by = swz >> 3;          // gridDim.x == 8
  int m0 = bx * 256, n0 = by * 256;

  int t = threadIdx.x;
  int w = t >> 6, lane = t & 63;
  int wr = w >> 2, wc = w & 3;              // wave tile: 128 rows x 64 cols
  int lr = lane & 15, lq = lane >> 4;

  // 32-bit element offsets (bases are SGPR kernel args -> saddr form)
  const unsigned abase = (unsigned)(m0 + wr * 128 + lr) * KBIG + lq * 8;
  const unsigned bbase = (unsigned)(n0 + wc * 64 + lr) * KBIG + lq * 8;

  f32x4 acc[8][4];
  #pragma unroll
  for (int i = 0; i < 8; ++i)
    #pragma unroll
    for (int j = 0; j < 4; ++j)
      acc[i][j] = (f32x4){0.f, 0.f, 0.f, 0.f};

  #define LOADF(AF, BF, KT) {                                                         \
    const unsigned kk_ = (unsigned)(KT) * 32;                                         \
    _Pragma("unroll")                                                                 \
    for (int i = 0; i < 8; ++i)                                                       \
      AF[i] = *(const short8*)(A + (abase + (unsigned)i * (16u * KBIG) + kk_));       \
    _Pragma("unroll")                                                                 \
    for (int j = 0; j < 4; ++j)                                                       \
      BF[j] = *(const short8*)(Bt + (bbase + (unsigned)j * (16u * KBIG) + kk_)); }

  #define MFMA_NP(AF, BF) {                                                           \
    _Pragma("unroll")                                                                 \
    for (int i = 0; i < 8; ++i)                                                       \
      _Pragma("unroll")                                                               \
      for (int j = 0; j < 4; ++j)                                                     \
        acc[i][j] = __builtin_amdgcn_mfma_f32_16x16x32_bf16(AF[i], BF[j], acc[i][j], 0, 0, 0); }

  short8 afA[8], bfA[4], afB[8], bfB[4];
  const int NT = KBIG >> 5;   // 64 K-tiles

  LOADF(afA, bfA, 0);
  for (int kt = 0; kt + 2 < NT; kt += 2) {
    LOADF(afB, bfB, kt + 1);     // prefetch next while MFMA current
    MFMA_NP(afA, bfA);
    LOADF(afA, bfA, kt + 2);
    MFMA_NP(afB, bfB);
  }
  LOADF(afB, bfB, NT - 1);
  MFMA_NP(afA, bfA);
  MFMA_NP(afB, bfB);

  #undef LOADF
  #undef MFMA_NP

  // epilogue: scatter cols -> per-batch layout
  #pragma unroll
  for (int i = 0; i < 8; ++i) {
    #pragma unroll
    for (int j = 0; j < 4; ++j) {
      int col = n0 + wc * 64 + j * 16 + lr;
      int b = col >> 9, kc = col & 511;
      float* ob = outF + (long long)b * ((long long)M * 512) + kc;
      #pragma unroll
      for (int r = 0; r < 4; ++r) {
        int row = m0 + wr * 128 + i * 16 + lq * 4 + r;
        ob[(long long)row * 512] = acc[i][j][r];
      }
    }
  }
}

// ============ fallback (round-1 kernel) for small-ws path ============
#define BMT 128
#define BNT 128
#define BKT 32
#define LDSP 40

template<int MODE>
__global__ __launch_bounds__(256) void gemm_bt(
    const u16* __restrict__ A, const u16* __restrict__ Bt,
    const float* __restrict__ bias, const float* __restrict__ fixmat,
    float* __restrict__ outF, u16* __restrict__ outB,
    int M, int N, int K, long long out_batch_stride, int bt_batch_stride) {
  __shared__ u16 sA[BMT][LDSP];
  __shared__ u16 sB[BNT][LDSP];
  int b = blockIdx.z;
  const u16* Bt_b = Bt + (long long)b * bt_batch_stride;
  const float* fixrow = (MODE == 2) ? (fixmat + (long long)b * K) : nullptr;
  float* out_b = (MODE != 0) ? (outF + (long long)b * out_batch_stride) : nullptr;

  int m0 = blockIdx.y * BMT, n0 = blockIdx.x * BNT;
  int t = threadIdx.x;
  int wid = t >> 6, lane = t & 63;
  int wm = (wid >> 1) * 64, wn = (wid & 1) * 64;
  int lr = lane & 15, lq = lane >> 4;

  f32x4 acc[4][4];
  #pragma unroll
  for (int i = 0; i < 4; ++i)
    #pragma unroll
    for (int j = 0; j < 4; ++j)
      acc[i][j] = (f32x4){0.f, 0.f, 0.f, 0.f};

  int srow = t >> 1, scg = (t & 1) * 16;

  for (int k0 = 0; k0 < K; k0 += BKT) {
    {
      const u16* src = A + (long long)(m0 + srow) * K + k0 + scg;
      short8 v0 = *(const short8*)(src);
      short8 v1 = *(const short8*)(src + 8);
      *(short8*)&sA[srow][scg] = v0;
      *(short8*)&sA[srow][scg + 8] = v1;
    }
    {
      const u16* src = Bt_b + (long long)(n0 + srow) * K + k0 + scg;
      short8 v0 = *(const short8*)(src);
      short8 v1 = *(const short8*)(src + 8);
      if (MODE == 2) {
        u16* p0 = (u16*)&v0; u16* p1 = (u16*)&v1;
        #pragma unroll
        for (int j = 0; j < 8; ++j) {
          p0[j] = f2b(b2f(p0[j]) * fixrow[k0 + scg + j]);
          p1[j] = f2b(b2f(p1[j]) * fixrow[k0 + scg + 8 + j]);
        }
      }
      *(short8*)&sB[srow][scg] = v0;
      *(short8*)&sB[srow][scg + 8] = v1;
    }
    __syncthreads();
    short8 af[4], bf[4];
    #pragma unroll
    for (int i = 0; i < 4; ++i)
      af[i] = *(const short8*)&sA[wm + i * 16 + lr][lq * 8];
    #pragma unroll
    for (int j = 0; j < 4; ++j)
      bf[j] = *(const short8*)&sB[wn + j * 16 + lr][lq * 8];
    #pragma unroll
    for (int i = 0; i < 4; ++i)
      #pragma unroll
      for (int j = 0; j < 4; ++j)
        acc[i][j] = __builtin_amdgcn_mfma_f32_16x16x32_bf16(af[i], bf[j], acc[i][j], 0, 0, 0);
    __syncthreads();
  }

  #pragma unroll
  for (int i = 0; i < 4; ++i) {
    #pragma unroll
    for (int j = 0; j < 4; ++j) {
      int col = n0 + wn + j * 16 + lr;
      #pragma unroll
      for (int r = 0; r < 4; ++r) {
        int row = m0 + wm + i * 16 + lq * 4 + r;
        float v = acc[i][j][r];
        if (MODE == 0) {
          v += bias[col];
          outB[(long long)row * N + col] = f2b(v);
        } else {
          out_b[(long long)row * N + col] = v;
        }
      }
    }
  }
}

extern "C" void kernel_launch(void* const* d_in, const int* in_sizes, int n_in,
                              void* d_out, int out_size, void* d_ws, size_t ws_size,
                              hipStream_t stream) {
  const float* main_feat  = (const float*)d_in[0];
  const float* other_feat = (const float*)d_in[1];
  const float* fix_feat   = (const float*)d_in[2];
  const int*   mask       = (const int*)d_in[3];
  const float* Wq         = (const float*)d_in[4];
  const float* bq         = (const float*)d_in[5];
  const float* Wk         = (const float*)d_in[6];
  const float* bk         = (const float*)d_in[7];
  float* out = (float*)d_out;

  char* ws = (char*)d_ws;
  const size_t OFF_MAINB  = 0;
  const size_t OFF_OTHERB = 2097152;
  const size_t OFF_WQB    = 4194304;
  const size_t OFF_WKB    = 4718592;
  const size_t OFF_QB     = 5242880;
  const size_t OFF_KB     = 7340032;
  const size_t OFF_OTB    = 9437184;
  const size_t OFF_P      = 11534336;
  const size_t OFF_S      = 19922944;
  const size_t OFF_SCALED = 36700160;
  const size_t NEED_SCALED = OFF_SCALED + (size_t)BATCH_ * 512 * 2048 * 2;

  u16* mainB  = (u16*)(ws + OFF_MAINB);
  u16* otherB = (u16*)(ws + OFF_OTHERB);
  u16* WqB    = (u16*)(ws + OFF_WQB);
  u16* WkB    = (u16*)(ws + OFF_WKB);
  u16* QB     = (u16*)(ws + OFF_QB);
  u16* KB     = (u16*)(ws + OFF_KB);
  u16* oTB    = (u16*)(ws + OFF_OTB);
  u16* P      = (u16*)(ws + OFF_P);
  float* S    = (float*)(ws + OFF_S);
  u16* scaled = (u16*)(ws + OFF_SCALED);
  bool use_scaled = (ws_size >= NEED_SCALED);

  // 1) bf16 conversions
  cvt_bf16<<<1024, 256, 0, stream>>>(main_feat, mainB, 2048 * 512);
  cvt_bf16<<<1024, 256, 0, stream>>>(other_feat, otherB, 2048 * 512);
  cvt_bf16<<<256, 256, 0, stream>>>(Wq, WqB, 512 * 512);
  cvt_bf16<<<256, 256, 0, stream>>>(Wk, WkB, 512 * 512);
  // 2) otherT bf16 [512][2048]
  transpose_cvt<<<dim3(16, 64), 256, 0, stream>>>(other_feat, oTB, 2048, 512);

  if (use_scaled) {
    // 3) fused Q|K projection
    gemm_lds<0><<<dim3(4, 32), 256, 0, stream>>>(mainB, WqB, bq, WkB, bk,
        nullptr, QB, 4096, 512, 512);
    // 4) S = Q @ K^T
    gemm_lds<1><<<dim3(16, 16), 256, 0, stream>>>(QB, KB, nullptr, nullptr, nullptr,
        S, nullptr, 2048, 2048, 512);
    // 5) masked softmax -> P bf16
    softmax_mask<<<2048, 256, 0, stream>>>(S, mask, P, 2048);
    // 6) scaled as Bt [16384][2048]
    build_scaled<<<32768, 256, 0, stream>>>(oTB, fix_feat, scaled);
    // 7) LDS-free direct GEMM: out[b][m][k] via col scatter
    gemm_direct<<<dim3(8, 64), 512, 0, stream>>>(P, scaled, out, 2048, 16384);
  } else {
    gemm_bt<0><<<dim3(4, 16, 1), 256, 0, stream>>>(mainB, WqB, bq, nullptr,
        nullptr, QB, 2048, 512, 512, 0, 0);
    gemm_bt<0><<<dim3(4, 16, 1), 256, 0, stream>>>(otherB, WkB, bk, nullptr,
        nullptr, KB, 2048, 512, 512, 0, 0);
    gemm_bt<1><<<dim3(16, 16, 1), 256, 0, stream>>>(QB, KB, nullptr, nullptr,
        S, nullptr, 2048, 2048, 512, 0, 0);
    softmax_mask<<<2048, 256, 0, stream>>>(S, mask, P, 2048);
    gemm_bt<2><<<dim3(4, 16, BATCH_), 256, 0, stream>>>(P, oTB, nullptr, fix_feat,
        out, nullptr, 2048, 512, 2048, 1048576LL, 0);
  }
}

// Round 13
// 252.934 us; speedup vs baseline: 9.5321x; 1.6699x over previous
//
#include <hip/hip_runtime.h>
#include <hip/hip_bf16.h>

typedef unsigned short u16;
typedef __attribute__((ext_vector_type(8))) short short8;
typedef __attribute__((ext_vector_type(4))) float f32x4;

#define BATCH_ 32

static __device__ __forceinline__ float b2f(u16 u) {
  union { unsigned int i; float f; } v; v.i = ((unsigned int)u) << 16; return v.f;
}
static __device__ __forceinline__ u16 f2b(float x) {
  unsigned int i = __float_as_uint(x);
  unsigned int r = (i + 0x7fffu + ((i >> 16) & 1u)) >> 16;
  return (u16)r;
}

#define GCAST(p) ((const __attribute__((address_space(1))) void*)(p))
#define LCAST(p) ((__attribute__((address_space(3))) void*)(p))

// ---- elementwise f32 -> bf16 (n % 4 == 0)
__global__ __launch_bounds__(256) void cvt_bf16(const float* __restrict__ src,
                                                u16* __restrict__ dst, int n) {
  int i = (blockIdx.x * 256 + threadIdx.x) * 4;
  if (i >= n) return;
  float4 v = *(const float4*)(src + i);
  ushort4 o;
  o.x = f2b(v.x); o.y = f2b(v.y); o.z = f2b(v.z); o.w = f2b(v.w);
  *(ushort4*)(dst + i) = o;
}

// ---- transpose f32 [R][C] -> bf16 [C][R]
__global__ __launch_bounds__(256) void transpose_cvt(const float* __restrict__ src,
                                                     u16* __restrict__ dst, int R, int C) {
  __shared__ float tile[32][33];
  int c0 = blockIdx.x * 32, r0 = blockIdx.y * 32;
  int tx = threadIdx.x & 31, ty = threadIdx.x >> 5;
  #pragma unroll
  for (int i = 0; i < 32; i += 8)
    tile[ty + i][tx] = src[(long long)(r0 + ty + i) * C + c0 + tx];
  __syncthreads();
  #pragma unroll
  for (int i = 0; i < 32; i += 8)
    dst[(long long)(c0 + ty + i) * R + r0 + tx] = f2b(tile[tx][ty + i]);
}

// ---- scaled[b][k][o] = otherT[k][o] * fix[b][o]   (bf16)
__global__ __launch_bounds__(256) void build_scaled(const u16* __restrict__ oT,
                                                    const float* __restrict__ fix,
                                                    u16* __restrict__ out) {
  long long i4 = (long long)blockIdx.x * 256 + threadIdx.x; // group of 4 along o
  int o = (int)(i4 & 511) * 4;
  long long bk = i4 >> 9;            // b*512 + kk
  int b = (int)(bk >> 9);
  int kk = (int)(bk & 511);
  ushort4 v = *(const ushort4*)(oT + (long long)kk * 2048 + o);
  float4 f = *(const float4*)(fix + (long long)b * 2048 + o);
  ushort4 r;
  r.x = f2b(b2f(v.x) * f.x); r.y = f2b(b2f(v.y) * f.y);
  r.z = f2b(b2f(v.z) * f.z); r.w = f2b(b2f(v.w) * f.w);
  *(ushort4*)(out + bk * 2048 + o) = r;
}

// ---- masked row softmax: P[row][:] = softmax(S[row][:] * 1/sqrt(512), mask)
__global__ __launch_bounds__(256) void softmax_mask(const float* __restrict__ S,
                                                    const int* __restrict__ mask,
                                                    u16* __restrict__ P, int N) {
  const float scale = 0.044194173824159216f; // 1/sqrt(512)
  int row = blockIdx.x;
  int t = threadIdx.x;
  long long base = (long long)row * N;
  float vals[8]; int msk[8];
  float mx = -3.0e38f;
  #pragma unroll
  for (int i = 0; i < 8; ++i) {
    int c = t + i * 256;
    float s = S[base + c] * scale;
    int m = mask[base + c];
    vals[i] = s; msk[i] = m;
    if (!m) mx = fmaxf(mx, s);
  }
  #pragma unroll
  for (int off = 32; off; off >>= 1) mx = fmaxf(mx, __shfl_xor(mx, off));
  __shared__ float sred[4];
  if ((t & 63) == 0) sred[t >> 6] = mx;
  __syncthreads();
  mx = fmaxf(fmaxf(sred[0], sred[1]), fmaxf(sred[2], sred[3]));
  __syncthreads();
  float e[8]; float sum = 0.f;
  #pragma unroll
  for (int i = 0; i < 8; ++i) {
    e[i] = msk[i] ? 0.f : __expf(vals[i] - mx);
    sum += e[i];
  }
  #pragma unroll
  for (int off = 32; off; off >>= 1) sum += __shfl_xor(sum, off);
  if ((t & 63) == 0) sred[t >> 6] = sum;
  __syncthreads();
  sum = sred[0] + sred[1] + sred[2] + sred[3];
  float inv = (sum > 0.f) ? (1.f / sum) : 0.f;
  #pragma unroll
  for (int i = 0; i < 8; ++i) {
    int c = t + i * 256;
    P[base + c] = f2b(e[i] * inv);
  }
}

// ========== r2-proven 128x128 / BK=32 GEMM (small GEMMs: Q|K proj, S) ======
#define GBM 128
#define GBN 128
#define GBK 32

template<int EPI>
__global__ __launch_bounds__(256) void gemm_lds(
    const u16* __restrict__ A, const u16* __restrict__ Bt,
    const float* __restrict__ bias,
    const u16* __restrict__ Bt2, const float* __restrict__ bias2,
    float* __restrict__ outF, u16* __restrict__ outB,
    int M, int N, int K) {
  __shared__ u16 sA[GBM * GBK];
  __shared__ u16 sB[GBN * GBK];
  int m0 = blockIdx.y * GBM, n0 = blockIdx.x * GBN;
  if (EPI == 0) {
    if (2 * blockIdx.y >= gridDim.y) { Bt = Bt2; bias = bias2; }
  }
  int t = threadIdx.x;
  int wid = t >> 6, lane = t & 63;
  int wm = (wid >> 1) * 64, wn = (wid & 1) * 64;
  int lr = lane & 15, lq = lane >> 4;
  int srow = lane >> 2, schunk = (lane & 3) * 8;

  f32x4 acc[4][4];
  #pragma unroll
  for (int i = 0; i < 4; ++i)
    #pragma unroll
    for (int j = 0; j < 4; ++j)
      acc[i][j] = (f32x4){0.f, 0.f, 0.f, 0.f};

  const u16* gA = A + (long long)(m0 + wid * 32 + srow) * K + schunk;
  const u16* gB = Bt + (long long)(n0 + wid * 32 + srow) * K + schunk;
  u16* lA = &sA[(wid * 32) * GBK];
  u16* lB = &sB[(wid * 32) * GBK];
  const long long rowskip = (long long)16 * K;

  for (int k0 = 0; k0 < K; k0 += GBK) {
    __builtin_amdgcn_global_load_lds(GCAST(gA + k0),           LCAST(lA),            16, 0, 0);
    __builtin_amdgcn_global_load_lds(GCAST(gA + k0 + rowskip), LCAST(lA + 16 * GBK), 16, 0, 0);
    __builtin_amdgcn_global_load_lds(GCAST(gB + k0),           LCAST(lB),            16, 0, 0);
    __builtin_amdgcn_global_load_lds(GCAST(gB + k0 + rowskip), LCAST(lB + 16 * GBK), 16, 0, 0);
    __syncthreads();
    short8 af[4], bf[4];
    #pragma unroll
    for (int i = 0; i < 4; ++i)
      af[i] = *(const short8*)&sA[(wm + i * 16 + lr) * GBK + lq * 8];
    #pragma unroll
    for (int j = 0; j < 4; ++j)
      bf[j] = *(const short8*)&sB[(wn + j * 16 + lr) * GBK + lq * 8];
    #pragma unroll
    for (int i = 0; i < 4; ++i)
      #pragma unroll
      for (int j = 0; j < 4; ++j)
        acc[i][j] = __builtin_amdgcn_mfma_f32_16x16x32_bf16(af[i], bf[j], acc[i][j], 0, 0, 0);
    __syncthreads();
  }

  #pragma unroll
  for (int i = 0; i < 4; ++i) {
    #pragma unroll
    for (int j = 0; j < 4; ++j) {
      int col = n0 + wn + j * 16 + lr;
      #pragma unroll
      for (int r = 0; r < 4; ++r) {
        int row = m0 + wm + i * 16 + lq * 4 + r;
        float v = acc[i][j][r];
        if (EPI == 0) {
          outB[(long long)row * N + col] = f2b(v + bias[col]);
        } else {
          outF[(long long)row * N + col] = v;
        }
      }
    }
  }
}

// ========== ring-2 256x128 GEMM, 48KB LDS -> 2-3 blocks/CU ================
// Cross-block overlap (m114): multiple independent blocks per CU cover each
// other's read/barrier phases. 8 waves (4M x 2N), wave tile 64x64, BK=32.
// Pipeline identical to R11's correctness-proven ring-2: RD next-tile frags,
// STAGE tile kt+2 into the buffer whose reads drained last iter, MFMA from
// reg-prefetched frags, vmcnt(0)+lgkmcnt(0), barrier. Zero-conflict
// involution swizzle; SGB issue interleave {DS2 MFMA2}.
#define SGB __builtin_amdgcn_sched_group_barrier
// masks: MFMA=0x008, VMEM_READ=0x020, DS_READ=0x100

__global__ __launch_bounds__(512, 2) void gemm_ring(
    const u16* __restrict__ A, const u16* __restrict__ Bt,
    float* __restrict__ outF, int M, int N, int K) {
  __shared__ u16 lds[2][12288];   // [buf][A 8192 | B 4096] u16 = 48 KiB

  // XCD-chunked swizzle: XCD owns contiguous N-chunk, M fastest inside.
  int nwg = gridDim.x * gridDim.y;
  int wg = blockIdx.y * gridDim.x + blockIdx.x;
  int cpx = nwg >> 3;
  int swz = (wg & 7) * cpx + (wg >> 3);
  int bx = swz & 7, by = swz >> 3;          // gridDim.x == 8 (M tiles)
  int m0 = bx * 256, n0 = by * 128;

  int t = threadIdx.x;
  int w = t >> 6, lane = t & 63;
  int wr = w >> 1, wc = w & 1;              // wave tile: 64 rows x 64 cols
  int lr = lane & 15, lq = lane >> 4;
  int csw = (((lr >> 1) & 3) ^ lq) * 8;     // swizzled slot offset (u16), 2-way

  // staging source (pre-swizzled): thread t covers row (t>>2), slot (t&3)
  int srow = t >> 2;                                  // 0..127
  int sgc = (((srow >> 1) & 3) ^ (t & 3)) * 8;        // inverse-swizzled chunk
  const u16* pA0 = A + (long long)(m0 + srow) * K + sgc;
  const u16* pA1 = pA0 + (long long)128 * K;          // rows 128..255
  const u16* pB0 = Bt + (long long)(n0 + srow) * K + sgc;
  const int lbase = (w * 16) * 32;           // wave-uniform LDS base (u16)

  f32x4 acc[4][4];
  #pragma unroll
  for (int i = 0; i < 4; ++i)
    #pragma unroll
    for (int j = 0; j < 4; ++j)
      acc[i][j] = (f32x4){0.f, 0.f, 0.f, 0.f};

  const int NT = K >> 5;   // K/32 tiles (=64, even)

  #define STAGE_TILE(KT, SB_)                                                         \
    do {                                                                              \
      long long cofs = (long long)(KT) * 32;                                          \
      __builtin_amdgcn_global_load_lds(GCAST(pA0 + cofs), LCAST(&lds[SB_][lbase]),         16, 0, 0); \
      __builtin_amdgcn_global_load_lds(GCAST(pA1 + cofs), LCAST(&lds[SB_][4096 + lbase]),  16, 0, 0); \
      __builtin_amdgcn_global_load_lds(GCAST(pB0 + cofs), LCAST(&lds[SB_][8192 + lbase]),  16, 0, 0); \
    } while (0)

  #define RD_FRAGS(AF, BF, BUF) {                                                     \
    _Pragma("unroll")                                                                 \
    for (int i = 0; i < 4; ++i)                                                       \
      AF[i] = *(const short8*)&lds[BUF][(wr * 64 + i * 16 + lr) * 32 + csw];          \
    _Pragma("unroll")                                                                 \
    for (int j = 0; j < 4; ++j)                                                       \
      BF[j] = *(const short8*)&lds[BUF][8192 + (wc * 64 + j * 16 + lr) * 32 + csw]; }

  #define MFMA_NP(AF, BF) {                                                           \
    _Pragma("unroll")                                                                 \
    for (int i = 0; i < 4; ++i)                                                       \
      _Pragma("unroll")                                                               \
      for (int j = 0; j < 4; ++j)                                                     \
        acc[i][j] = __builtin_amdgcn_mfma_f32_16x16x32_bf16(AF[i], BF[j], acc[i][j], 0, 0, 0); }

  // issue-interleave: MFMA2 | {DS2 MFMA2}x4 | VMEM3 | MFMA6  (16 MFMA, 8 DS, 3 VM)
  #define SGB_TAIL() {                                                                \
    SGB(0x008, 2, 0);                                                                 \
    SGB(0x100, 2, 0); SGB(0x008, 2, 0);                                               \
    SGB(0x100, 2, 0); SGB(0x008, 2, 0);                                               \
    SGB(0x100, 2, 0); SGB(0x008, 2, 0);                                               \
    SGB(0x100, 2, 0); SGB(0x008, 2, 0);                                               \
    SGB(0x020, 3, 0);                                                                 \
    SGB(0x008, 6, 0); }

  #define IT_SYNC() do {                                                              \
    __builtin_amdgcn_sched_barrier(0);                                                \
    asm volatile("s_waitcnt vmcnt(0) lgkmcnt(0)" ::: "memory");                       \
    __builtin_amdgcn_s_barrier();                                                     \
    __builtin_amdgcn_sched_barrier(0);                                                \
  } while (0)

  short8 afA[4], bfA[4], afB[4], bfB[4];

  // prologue: stage tiles 0,1; drain; barrier; read tile 0 into regs
  STAGE_TILE(0, 0);
  STAGE_TILE(1, 1);
  asm volatile("s_waitcnt vmcnt(0)" ::: "memory");
  __builtin_amdgcn_s_barrier();
  __builtin_amdgcn_sched_barrier(0);
  RD_FRAGS(afA, bfA, 0);                     // regs <- tile 0
  asm volatile("s_waitcnt lgkmcnt(0)" ::: "memory");  // protect vs STAGE(2)->buf0
  __builtin_amdgcn_sched_barrier(0);

  // steady: 2 iters/body. Invariant at iter kt: tile kt in regs, tile kt+1
  // resident in buf[(kt+1)&1], buf[kt&1] free (all waves' reads drained).
  for (int kt = 0; kt + 2 < NT; kt += 2) {
    // ---- iter kt (cur = A)
    RD_FRAGS(afB, bfB, 1);                   // tile kt+1 (resident)
    STAGE_TILE(kt + 2, 0);                   // overwrite tile kt's buffer
    MFMA_NP(afA, bfA);                       // tile kt
    SGB_TAIL();
    IT_SYNC();
    // ---- iter kt+1 (cur = B)
    RD_FRAGS(afA, bfA, 0);                   // tile kt+2
    STAGE_TILE(kt + 3, 1);                   // kt+3 <= NT-1 in this loop
    MFMA_NP(afB, bfB);
    SGB_TAIL();
    IT_SYNC();
  }

  // tail: tiles NT-2 (in regs afA), NT-1 (in buf1)
  RD_FRAGS(afB, bfB, 1);                     // tile NT-1
  __builtin_amdgcn_sched_barrier(0);
  __builtin_amdgcn_s_setprio(1);
  MFMA_NP(afA, bfA);                         // tile NT-2
  __builtin_amdgcn_s_setprio(0);
  __builtin_amdgcn_sched_barrier(0);
  asm volatile("s_waitcnt lgkmcnt(0)" ::: "memory");
  __builtin_amdgcn_s_setprio(1);
  MFMA_NP(afB, bfB);                         // tile NT-1
  __builtin_amdgcn_s_setprio(0);

  #undef STAGE_TILE
  #undef RD_FRAGS
  #undef MFMA_NP
  #undef SGB_TAIL
  #undef IT_SYNC

  // epilogue: scatter cols -> per-batch layout
  #pragma unroll
  for (int i = 0; i < 4; ++i) {
    #pragma unroll
    for (int j = 0; j < 4; ++j) {
      int col = n0 + wc * 64 + j * 16 + lr;
      int b = col >> 9, kc = col & 511;
      float* ob = outF + (long long)b * ((long long)M * 512) + kc;
      #pragma unroll
      for (int r = 0; r < 4; ++r) {
        int row = m0 + wr * 64 + i * 16 + lq * 4 + r;
        ob[(long long)row * 512] = acc[i][j][r];
      }
    }
  }
}

// ============ fallback (round-1 kernel) for small-ws path ============
#define BMT 128
#define BNT 128
#define BKT 32
#define LDSP 40

template<int MODE>
__global__ __launch_bounds__(256) void gemm_bt(
    const u16* __restrict__ A, const u16* __restrict__ Bt,
    const float* __restrict__ bias, const float* __restrict__ fixmat,
    float* __restrict__ outF, u16* __restrict__ outB,
    int M, int N, int K, long long out_batch_stride, int bt_batch_stride) {
  __shared__ u16 sA[BMT][LDSP];
  __shared__ u16 sB[BNT][LDSP];
  int b = blockIdx.z;
  const u16* Bt_b = Bt + (long long)b * bt_batch_stride;
  const float* fixrow = (MODE == 2) ? (fixmat + (long long)b * K) : nullptr;
  float* out_b = (MODE != 0) ? (outF + (long long)b * out_batch_stride) : nullptr;

  int m0 = blockIdx.y * BMT, n0 = blockIdx.x * BNT;
  int t = threadIdx.x;
  int wid = t >> 6, lane = t & 63;
  int wm = (wid >> 1) * 64, wn = (wid & 1) * 64;
  int lr = lane & 15, lq = lane >> 4;

  f32x4 acc[4][4];
  #pragma unroll
  for (int i = 0; i < 4; ++i)
    #pragma unroll
    for (int j = 0; j < 4; ++j)
      acc[i][j] = (f32x4){0.f, 0.f, 0.f, 0.f};

  int srow = t >> 1, scg = (t & 1) * 16;

  for (int k0 = 0; k0 < K; k0 += BKT) {
    {
      const u16* src = A + (long long)(m0 + srow) * K + k0 + scg;
      short8 v0 = *(const short8*)(src);
      short8 v1 = *(const short8*)(src + 8);
      *(short8*)&sA[srow][scg] = v0;
      *(short8*)&sA[srow][scg + 8] = v1;
    }
    {
      const u16* src = Bt_b + (long long)(n0 + srow) * K + k0 + scg;
      short8 v0 = *(const short8*)(src);
      short8 v1 = *(const short8*)(src + 8);
      if (MODE == 2) {
        u16* p0 = (u16*)&v0; u16* p1 = (u16*)&v1;
        #pragma unroll
        for (int j = 0; j < 8; ++j) {
          p0[j] = f2b(b2f(p0[j]) * fixrow[k0 + scg + j]);
          p1[j] = f2b(b2f(p1[j]) * fixrow[k0 + scg + 8 + j]);
        }
      }
      *(short8*)&sB[srow][scg] = v0;
      *(short8*)&sB[srow][scg + 8] = v1;
    }
    __syncthreads();
    short8 af[4], bf[4];
    #pragma unroll
    for (int i = 0; i < 4; ++i)
      af[i] = *(const short8*)&sA[wm + i * 16 + lr][lq * 8];
    #pragma unroll
    for (int j = 0; j < 4; ++j)
      bf[j] = *(const short8*)&sB[wn + j * 16 + lr][lq * 8];
    #pragma unroll
    for (int i = 0; i < 4; ++i)
      #pragma unroll
      for (int j = 0; j < 4; ++j)
        acc[i][j] = __builtin_amdgcn_mfma_f32_16x16x32_bf16(af[i], bf[j], acc[i][j], 0, 0, 0);
    __syncthreads();
  }

  #pragma unroll
  for (int i = 0; i < 4; ++i) {
    #pragma unroll
    for (int j = 0; j < 4; ++j) {
      int col = n0 + wn + j * 16 + lr;
      #pragma unroll
      for (int r = 0; r < 4; ++r) {
        int row = m0 + wm + i * 16 + lq * 4 + r;
        float v = acc[i][j][r];
        if (MODE == 0) {
          v += bias[col];
          outB[(long long)row * N + col] = f2b(v);
        } else {
          out_b[(long long)row * N + col] = v;
        }
      }
    }
  }
}

extern "C" void kernel_launch(void* const* d_in, const int* in_sizes, int n_in,
                              void* d_out, int out_size, void* d_ws, size_t ws_size,
                              hipStream_t stream) {
  const float* main_feat  = (const float*)d_in[0];
  const float* other_feat = (const float*)d_in[1];
  const float* fix_feat   = (const float*)d_in[2];
  const int*   mask       = (const int*)d_in[3];
  const float* Wq         = (const float*)d_in[4];
  const float* bq         = (const float*)d_in[5];
  const float* Wk         = (const float*)d_in[6];
  const float* bk         = (const float*)d_in[7];
  float* out = (float*)d_out;

  char* ws = (char*)d_ws;
  const size_t OFF_MAINB  = 0;
  const size_t OFF_OTHERB = 2097152;
  const size_t OFF_WQB    = 4194304;
  const size_t OFF_WKB    = 4718592;
  const size_t OFF_QB     = 5242880;
  const size_t OFF_KB     = 7340032;
  const size_t OFF_OTB    = 9437184;
  const size_t OFF_P      = 11534336;
  const size_t OFF_S      = 19922944;
  const size_t OFF_SCALED = 36700160;
  const size_t NEED_SCALED = OFF_SCALED + (size_t)BATCH_ * 512 * 2048 * 2;

  u16* mainB  = (u16*)(ws + OFF_MAINB);
  u16* otherB = (u16*)(ws + OFF_OTHERB);
  u16* WqB    = (u16*)(ws + OFF_WQB);
  u16* WkB    = (u16*)(ws + OFF_WKB);
  u16* QB     = (u16*)(ws + OFF_QB);
  u16* KB     = (u16*)(ws + OFF_KB);
  u16* oTB    = (u16*)(ws + OFF_OTB);
  u16* P      = (u16*)(ws + OFF_P);
  float* S    = (float*)(ws + OFF_S);
  u16* scaled = (u16*)(ws + OFF_SCALED);
  bool use_scaled = (ws_size >= NEED_SCALED);

  // 1) bf16 conversions
  cvt_bf16<<<1024, 256, 0, stream>>>(main_feat, mainB, 2048 * 512);
  cvt_bf16<<<1024, 256, 0, stream>>>(other_feat, otherB, 2048 * 512);
  cvt_bf16<<<256, 256, 0, stream>>>(Wq, WqB, 512 * 512);
  cvt_bf16<<<256, 256, 0, stream>>>(Wk, WkB, 512 * 512);
  // 2) otherT bf16 [512][2048]
  transpose_cvt<<<dim3(16, 64), 256, 0, stream>>>(other_feat, oTB, 2048, 512);

  if (use_scaled) {
    // 3) fused Q|K projection
    gemm_lds<0><<<dim3(4, 32), 256, 0, stream>>>(mainB, WqB, bq, WkB, bk,
        nullptr, QB, 4096, 512, 512);
    // 4) S = Q @ K^T
    gemm_lds<1><<<dim3(16, 16), 256, 0, stream>>>(QB, KB, nullptr, nullptr, nullptr,
        S, nullptr, 2048, 2048, 512);
    // 5) masked softmax -> P bf16
    softmax_mask<<<2048, 256, 0, stream>>>(S, mask, P, 2048);
    // 6) scaled as Bt [16384][2048]
    build_scaled<<<32768, 256, 0, stream>>>(oTB, fix_feat, scaled);
    // 7) ring-2 256x128 GEMM (2-3 blocks/CU): out[b][m][k] via col scatter
    gemm_ring<<<dim3(8, 128), 512, 0, stream>>>(P, scaled, out, 2048, 16384, 2048);
  } else {
    gemm_bt<0><<<dim3(4, 16, 1), 256, 0, stream>>>(mainB, WqB, bq, nullptr,
        nullptr, QB, 2048, 512, 512, 0, 0);
    gemm_bt<0><<<dim3(4, 16, 1), 256, 0, stream>>>(otherB, WkB, bk, nullptr,
        nullptr, KB, 2048, 512, 512, 0, 0);
    gemm_bt<1><<<dim3(16, 16, 1), 256, 0, stream>>>(QB, KB, nullptr, nullptr,
        S, nullptr, 2048, 2048, 512, 0, 0);
    softmax_mask<<<2048, 256, 0, stream>>>(S, mask, P, 2048);
    gemm_bt<2><<<dim3(4, 16, BATCH_), 256, 0, stream>>>(P, oTB, nullptr, fix_feat,
        out, nullptr, 2048, 512, 2048, 1048576LL, 0);
  }
}

// Round 14
// 177.029 us; speedup vs baseline: 13.6193x; 1.4288x over previous
//
#include <hip/hip_runtime.h>
#include <hip/hip_bf16.h>

typedef unsigned short u16;
typedef __attribute__((ext_vector_type(8))) short short8;
typedef __attribute__((ext_vector_type(4))) float f32x4;

#define BATCH_ 32

static __device__ __forceinline__ float b2f(u16 u) {
  union { unsigned int i; float f; } v; v.i = ((unsigned int)u) << 16; return v.f;
}
static __device__ __forceinline__ u16 f2b(float x) {
  unsigned int i = __float_as_uint(x);
  unsigned int r = (i + 0x7fffu + ((i >> 16) & 1u)) >> 16;
  return (u16)r;
}

#define GCAST(p) ((const __attribute__((address_space(1))) void*)(p))
#define LCAST(p) ((__attribute__((address_space(3))) void*)(p))

// ---- dual-source f32 -> bf16 (n1, n2 % 4 == 0); one launch for two arrays
__global__ __launch_bounds__(256) void cvt_bf16_dual(
    const float* __restrict__ s1, u16* __restrict__ d1, int n1,
    const float* __restrict__ s2, u16* __restrict__ d2, int n2) {
  int i = (blockIdx.x * 256 + threadIdx.x) * 4;
  const float* s; u16* d; int idx;
  if (i < n1) { s = s1; d = d1; idx = i; }
  else { idx = i - n1; if (idx >= n2) return; s = s2; d = d2; }
  float4 v = *(const float4*)(s + idx);
  ushort4 o;
  o.x = f2b(v.x); o.y = f2b(v.y); o.z = f2b(v.z); o.w = f2b(v.w);
  *(ushort4*)(d + idx) = o;
}

// ---- fused transpose+scale: scaled[b][k][o] = other[o][k] * fix[b][o]
// other f32 [2048][512], fix f32 [32][2048], scaled bf16 [32*512][2048].
// block = 32x32 (o,k) tile; writes that tile for all 32 batches.
__global__ __launch_bounds__(256) void transpose_scale(
    const float* __restrict__ other, const float* __restrict__ fix,
    u16* __restrict__ scaled) {
  __shared__ float tile[32][33];   // [o_local][k_local]
  __shared__ float fixs[32][33];   // [b][o_local]
  int k0 = blockIdx.x * 32, o0 = blockIdx.y * 32;
  int tx = threadIdx.x & 31, ty = threadIdx.x >> 5;   // ty 0..7
  #pragma unroll
  for (int i = 0; i < 32; i += 8)
    tile[ty + i][tx] = other[(long long)(o0 + ty + i) * 512 + k0 + tx];
  #pragma unroll
  for (int i = 0; i < 32; i += 8)
    fixs[ty + i][tx] = fix[(long long)(ty + i) * 2048 + o0 + tx];
  __syncthreads();
  int kk = threadIdx.x >> 4;          // 0..15
  int oo = (threadIdx.x & 15) * 2;    // 0,2,..30
  #pragma unroll 4
  for (int b = 0; b < 32; ++b) {
    #pragma unroll
    for (int p = 0; p < 2; ++p) {
      int k = kk + p * 16;
      ushort2 w;
      w.x = f2b(tile[oo][k] * fixs[b][oo]);
      w.y = f2b(tile[oo + 1][k] * fixs[b][oo + 1]);
      *(ushort2*)(scaled + ((long long)(b * 512 + k0 + k) * 2048 + o0 + oo)) = w;
    }
  }
}

// ---- masked row softmax on bf16 S: P[row][:] = softmax(S*1/sqrt(512), mask)
__global__ __launch_bounds__(256) void softmax_mask(const u16* __restrict__ S,
                                                    const int* __restrict__ mask,
                                                    u16* __restrict__ P, int N) {
  const float scale = 0.044194173824159216f; // 1/sqrt(512)
  int row = blockIdx.x;
  int t = threadIdx.x;
  long long base = (long long)row * N;
  float vals[8]; int msk[8];
  float mx = -3.0e38f;
  #pragma unroll
  for (int i = 0; i < 8; ++i) {
    int c = t + i * 256;
    float s = b2f(S[base + c]) * scale;
    int m = mask[base + c];
    vals[i] = s; msk[i] = m;
    if (!m) mx = fmaxf(mx, s);
  }
  #pragma unroll
  for (int off = 32; off; off >>= 1) mx = fmaxf(mx, __shfl_xor(mx, off));
  __shared__ float sred[4];
  if ((t & 63) == 0) sred[t >> 6] = mx;
  __syncthreads();
  mx = fmaxf(fmaxf(sred[0], sred[1]), fmaxf(sred[2], sred[3]));
  __syncthreads();
  float e[8]; float sum = 0.f;
  #pragma unroll
  for (int i = 0; i < 8; ++i) {
    e[i] = msk[i] ? 0.f : __expf(vals[i] - mx);
    sum += e[i];
  }
  #pragma unroll
  for (int off = 32; off; off >>= 1) sum += __shfl_xor(sum, off);
  if ((t & 63) == 0) sred[t >> 6] = sum;
  __syncthreads();
  sum = sred[0] + sred[1] + sred[2] + sred[3];
  float inv = (sum > 0.f) ? (1.f / sum) : 0.f;
  #pragma unroll
  for (int i = 0; i < 8; ++i) {
    int c = t + i * 256;
    P[base + c] = f2b(e[i] * inv);
  }
}

// ========== r2-proven 128x128 / BK=32 GEMM (small GEMMs: Q|K proj, S) ======
// EPI 0: outB = bf16(C + bias[col]); dual-weight via second half of grid.y
// EPI 1: outF = C (f32)
// EPI 3: outB = bf16(C)           (bf16 S output)
#define GBM 128
#define GBN 128
#define GBK 32

template<int EPI>
__global__ __launch_bounds__(256) void gemm_lds(
    const u16* __restrict__ A, const u16* __restrict__ Bt,
    const float* __restrict__ bias,
    const u16* __restrict__ Bt2, const float* __restrict__ bias2,
    float* __restrict__ outF, u16* __restrict__ outB,
    int M, int N, int K) {
  __shared__ u16 sA[GBM * GBK];
  __shared__ u16 sB[GBN * GBK];
  int m0 = blockIdx.y * GBM, n0 = blockIdx.x * GBN;
  if (EPI == 0) {
    if (2 * blockIdx.y >= gridDim.y) { Bt = Bt2; bias = bias2; }
  }
  int t = threadIdx.x;
  int wid = t >> 6, lane = t & 63;
  int wm = (wid >> 1) * 64, wn = (wid & 1) * 64;
  int lr = lane & 15, lq = lane >> 4;
  int srow = lane >> 2, schunk = (lane & 3) * 8;

  f32x4 acc[4][4];
  #pragma unroll
  for (int i = 0; i < 4; ++i)
    #pragma unroll
    for (int j = 0; j < 4; ++j)
      acc[i][j] = (f32x4){0.f, 0.f, 0.f, 0.f};

  const u16* gA = A + (long long)(m0 + wid * 32 + srow) * K + schunk;
  const u16* gB = Bt + (long long)(n0 + wid * 32 + srow) * K + schunk;
  u16* lA = &sA[(wid * 32) * GBK];
  u16* lB = &sB[(wid * 32) * GBK];
  const long long rowskip = (long long)16 * K;

  for (int k0 = 0; k0 < K; k0 += GBK) {
    __builtin_amdgcn_global_load_lds(GCAST(gA + k0),           LCAST(lA),            16, 0, 0);
    __builtin_amdgcn_global_load_lds(GCAST(gA + k0 + rowskip), LCAST(lA + 16 * GBK), 16, 0, 0);
    __builtin_amdgcn_global_load_lds(GCAST(gB + k0),           LCAST(lB),            16, 0, 0);
    __builtin_amdgcn_global_load_lds(GCAST(gB + k0 + rowskip), LCAST(lB + 16 * GBK), 16, 0, 0);
    __syncthreads();
    short8 af[4], bf[4];
    #pragma unroll
    for (int i = 0; i < 4; ++i)
      af[i] = *(const short8*)&sA[(wm + i * 16 + lr) * GBK + lq * 8];
    #pragma unroll
    for (int j = 0; j < 4; ++j)
      bf[j] = *(const short8*)&sB[(wn + j * 16 + lr) * GBK + lq * 8];
    #pragma unroll
    for (int i = 0; i < 4; ++i)
      #pragma unroll
      for (int j = 0; j < 4; ++j)
        acc[i][j] = __builtin_amdgcn_mfma_f32_16x16x32_bf16(af[i], bf[j], acc[i][j], 0, 0, 0);
    __syncthreads();
  }

  #pragma unroll
  for (int i = 0; i < 4; ++i) {
    #pragma unroll
    for (int j = 0; j < 4; ++j) {
      int col = n0 + wn + j * 16 + lr;
      #pragma unroll
      for (int r = 0; r < 4; ++r) {
        int row = m0 + wm + i * 16 + lq * 4 + r;
        float v = acc[i][j][r];
        if (EPI == 0) {
          outB[(long long)row * N + col] = f2b(v + bias[col]);
        } else if (EPI == 1) {
          outF[(long long)row * N + col] = v;
        } else {
          outB[(long long)row * N + col] = f2b(v);
        }
      }
    }
  }
}

// ========== ring-4 counted-vmcnt 256x256 GEMM + reg prefetch + SGB =========
// R7-verbatim (benched 137.5us, MfmaUtil 45%, 0 conflicts).
#define SGB __builtin_amdgcn_sched_group_barrier
// masks: MFMA=0x008, VMEM_READ=0x020, DS_READ=0x100

__global__ __launch_bounds__(512, 2) void gemm_ring(
    const u16* __restrict__ A, const u16* __restrict__ Bt,
    float* __restrict__ outF, int M, int N, int K) {
  __shared__ u16 lds[4][2][8192];   // [ring][A/B][row*32 + slot*8] = 128 KiB

  // XCD-chunked swizzle: XCD owns contiguous N-chunk, M fastest inside.
  int nwg = gridDim.x * gridDim.y;
  int wg = blockIdx.y * gridDim.x + blockIdx.x;
  int cpx = nwg >> 3;
  int swz = (wg & 7) * cpx + (wg >> 3);
  int bx = swz & 7, by = swz >> 3;          // gridDim.x == 8
  int m0 = bx * 256, n0 = by * 256;

  int t = threadIdx.x;
  int w = t >> 6, lane = t & 63;
  int wr = w >> 2, wc = w & 3;              // wave tile: 128 rows x 64 cols
  int lr = lane & 15, lq = lane >> 4;
  int csw = (((lr >> 1) & 3) ^ lq) * 8;     // swizzled slot offset (u16)

  // staging source (pre-swizzled): thread t covers row (t>>2), slot (t&3)
  int srow = t >> 2;                                  // 0..127
  int sgc = (((srow >> 1) & 3) ^ (t & 3)) * 8;        // inverse-swizzled chunk
  const u16* pA0 = A + (long long)(m0 + srow) * K + sgc;
  const u16* pA1 = pA0 + (long long)128 * K;
  const u16* pB0 = Bt + (long long)(n0 + srow) * K + sgc;
  const u16* pB1 = pB0 + (long long)128 * K;
  const int lbase = (w * 16) * 32;           // wave-uniform LDS base (u16)

  f32x4 acc[8][4];
  #pragma unroll
  for (int i = 0; i < 8; ++i)
    #pragma unroll
    for (int j = 0; j < 4; ++j)
      acc[i][j] = (f32x4){0.f, 0.f, 0.f, 0.f};

  const int NT = K >> 5;   // K/32 tiles (=64)

  #define STAGE_TILE(KT, SB)                                                          \
    do {                                                                              \
      long long cofs = (long long)(KT) * 32;                                          \
      __builtin_amdgcn_global_load_lds(GCAST(pA0 + cofs), LCAST(&lds[SB][0][lbase]),            16, 0, 0); \
      __builtin_amdgcn_global_load_lds(GCAST(pA1 + cofs), LCAST(&lds[SB][0][lbase + 128 * 32]), 16, 0, 0); \
      __builtin_amdgcn_global_load_lds(GCAST(pB0 + cofs), LCAST(&lds[SB][1][lbase]),            16, 0, 0); \
      __builtin_amdgcn_global_load_lds(GCAST(pB1 + cofs), LCAST(&lds[SB][1][lbase + 128 * 32]), 16, 0, 0); \
    } while (0)

  #define RD_FRAGS(AF, BF, BUF) {                                                     \
    _Pragma("unroll")                                                                 \
    for (int i = 0; i < 8; ++i)                                                       \
      AF[i] = *(const short8*)&lds[BUF][0][(wr * 128 + i * 16 + lr) * 32 + csw];      \
    _Pragma("unroll")                                                                 \
    for (int j = 0; j < 4; ++j)                                                       \
      BF[j] = *(const short8*)&lds[BUF][1][(wc * 64 + j * 16 + lr) * 32 + csw]; }

  #define MFMA_NP(AF, BF) {                                                           \
    _Pragma("unroll")                                                                 \
    for (int i = 0; i < 8; ++i)                                                       \
      _Pragma("unroll")                                                               \
      for (int j = 0; j < 4; ++j)                                                     \
        acc[i][j] = __builtin_amdgcn_mfma_f32_16x16x32_bf16(AF[i], BF[j], acc[i][j], 0, 0, 0); }

  #define MFMA_BLK(AF, BF) {                                                          \
    __builtin_amdgcn_s_setprio(1);                                                    \
    MFMA_NP(AF, BF);                                                                  \
    __builtin_amdgcn_s_setprio(0); }

  // issue-interleave directive tail: {MFMA2} {DS2,MFMA4}x3 {VMEM4} {DS2,MFMA4}x3 {MFMA6}
  #define SGB_TAIL() {                                                                \
    SGB(0x008, 2, 0);                                                                 \
    SGB(0x100, 2, 0); SGB(0x008, 4, 0);                                               \
    SGB(0x100, 2, 0); SGB(0x008, 4, 0);                                               \
    SGB(0x100, 2, 0); SGB(0x008, 4, 0);                                               \
    SGB(0x020, 4, 0);                                                                 \
    SGB(0x100, 2, 0); SGB(0x008, 4, 0);                                               \
    SGB(0x100, 2, 0); SGB(0x008, 4, 0);                                               \
    SGB(0x100, 2, 0); SGB(0x008, 4, 0);                                               \
    SGB(0x008, 6, 0); }

  short8 afA[8], bfA[4], afB[8], bfB[4];

  // prologue: stage tiles 0,1,2 (12 loads); vmcnt(4) -> tiles 0,1 resident
  STAGE_TILE(0, 0);
  STAGE_TILE(1, 1);
  STAGE_TILE(2, 2);
  asm volatile("s_waitcnt vmcnt(4)" ::: "memory");
  __builtin_amdgcn_s_barrier();
  __builtin_amdgcn_sched_barrier(0);
  RD_FRAGS(afA, bfA, 0);                     // regs <- tile 0

  // steady state: 2 iters per body; invariant at iter kt entry:
  //   tiles <= kt+1 LDS-resident, tile kt+2's 4 loads outstanding.
  for (int kt = 0; kt + 4 < NT; kt += 2) {
    // ---- iter kt (cur = A)
    RD_FRAGS(afB, bfB, ((kt + 1) & 3));      // regs <- tile kt+1 (resident)
    STAGE_TILE(kt + 3, ((kt + 3) & 3));      // outstanding: kt+2, kt+3 (8)
    MFMA_NP(afA, bfA);                       // tile kt; interleaved via SGB
    SGB_TAIL();
    asm volatile("s_waitcnt vmcnt(4)" ::: "memory");   // tile kt+2 resident
    __builtin_amdgcn_s_barrier();
    __builtin_amdgcn_sched_barrier(0);
    // ---- iter kt+1 (cur = B)
    RD_FRAGS(afA, bfA, ((kt + 2) & 3));
    STAGE_TILE(kt + 4, ((kt + 4) & 3));
    MFMA_NP(afB, bfB);
    SGB_TAIL();
    asm volatile("s_waitcnt vmcnt(4)" ::: "memory");
    __builtin_amdgcn_s_barrier();
    __builtin_amdgcn_sched_barrier(0);
  }

  // tail: iters NT-4 .. NT-1 (steady loop ended at iter NT-5, parity even)
  // iter NT-4 (cur = A)
  RD_FRAGS(afB, bfB, ((NT - 3) & 3));
  STAGE_TILE(NT - 1, ((NT - 1) & 3));
  __builtin_amdgcn_sched_barrier(0);
  MFMA_BLK(afA, bfA);
  __builtin_amdgcn_sched_barrier(0);
  asm volatile("s_waitcnt vmcnt(4)" ::: "memory");     // tile NT-2 resident
  __builtin_amdgcn_s_barrier();
  __builtin_amdgcn_sched_barrier(0);
  // iter NT-3 (cur = B)
  RD_FRAGS(afA, bfA, ((NT - 2) & 3));
  __builtin_amdgcn_sched_barrier(0);
  MFMA_BLK(afB, bfB);
  __builtin_amdgcn_sched_barrier(0);
  asm volatile("s_waitcnt vmcnt(0)" ::: "memory");     // tile NT-1 resident
  __builtin_amdgcn_s_barrier();
  __builtin_amdgcn_sched_barrier(0);
  // iter NT-2 (cur = A)
  RD_FRAGS(afB, bfB, ((NT - 1) & 3));
  __builtin_amdgcn_sched_barrier(0);
  MFMA_BLK(afA, bfA);
  // iter NT-1 (cur = B) -- pure register MFMA, no barrier needed
  MFMA_BLK(afB, bfB);

  #undef STAGE_TILE
  #undef RD_FRAGS
  #undef MFMA_NP
  #undef MFMA_BLK
  #undef SGB_TAIL

  // epilogue: scatter cols -> per-batch layout
  #pragma unroll
  for (int i = 0; i < 8; ++i) {
    #pragma unroll
    for (int j = 0; j < 4; ++j) {
      int col = n0 + wc * 64 + j * 16 + lr;
      int b = col >> 9, kc = col & 511;
      float* ob = outF + (long long)b * ((long long)M * 512) + kc;
      #pragma unroll
      for (int r = 0; r < 4; ++r) {
        int row = m0 + wr * 128 + i * 16 + lq * 4 + r;
        ob[(long long)row * 512] = acc[i][j][r];
      }
    }
  }
}

// ---- transpose f32 [R][C] -> bf16 [C][R]  (fallback path only)
__global__ __launch_bounds__(256) void transpose_cvt(const float* __restrict__ src,
                                                     u16* __restrict__ dst, int R, int C) {
  __shared__ float tile[32][33];
  int c0 = blockIdx.x * 32, r0 = blockIdx.y * 32;
  int tx = threadIdx.x & 31, ty = threadIdx.x >> 5;
  #pragma unroll
  for (int i = 0; i < 32; i += 8)
    tile[ty + i][tx] = src[(long long)(r0 + ty + i) * C + c0 + tx];
  __syncthreads();
  #pragma unroll
  for (int i = 0; i < 32; i += 8)
    dst[(long long)(c0 + ty + i) * R + r0 + tx] = f2b(tile[tx][ty + i]);
}

// ============ fallback (round-1 kernel) for small-ws path ============
#define BMT 128
#define BNT 128
#define BKT 32
#define LDSP 40

template<int MODE>
__global__ __launch_bounds__(256) void gemm_bt(
    const u16* __restrict__ A, const u16* __restrict__ Bt,
    const float* __restrict__ bias, const float* __restrict__ fixmat,
    float* __restrict__ outF, u16* __restrict__ outB,
    int M, int N, int K, long long out_batch_stride, int bt_batch_stride) {
  __shared__ u16 sA[BMT][LDSP];
  __shared__ u16 sB[BNT][LDSP];
  int b = blockIdx.z;
  const u16* Bt_b = Bt + (long long)b * bt_batch_stride;
  const float* fixrow = (MODE == 2) ? (fixmat + (long long)b * K) : nullptr;
  float* out_b = (MODE == 1 || MODE == 2) ? (outF + (long long)b * out_batch_stride) : nullptr;

  int m0 = blockIdx.y * BMT, n0 = blockIdx.x * BNT;
  int t = threadIdx.x;
  int wid = t >> 6, lane = t & 63;
  int wm = (wid >> 1) * 64, wn = (wid & 1) * 64;
  int lr = lane & 15, lq = lane >> 4;

  f32x4 acc[4][4];
  #pragma unroll
  for (int i = 0; i < 4; ++i)
    #pragma unroll
    for (int j = 0; j < 4; ++j)
      acc[i][j] = (f32x4){0.f, 0.f, 0.f, 0.f};

  int srow = t >> 1, scg = (t & 1) * 16;

  for (int k0 = 0; k0 < K; k0 += BKT) {
    {
      const u16* src = A + (long long)(m0 + srow) * K + k0 + scg;
      short8 v0 = *(const short8*)(src);
      short8 v1 = *(const short8*)(src + 8);
      *(short8*)&sA[srow][scg] = v0;
      *(short8*)&sA[srow][scg + 8] = v1;
    }
    {
      const u16* src = Bt_b + (long long)(n0 + srow) * K + k0 + scg;
      short8 v0 = *(const short8*)(src);
      short8 v1 = *(const short8*)(src + 8);
      if (MODE == 2) {
        u16* p0 = (u16*)&v0; u16* p1 = (u16*)&v1;
        #pragma unroll
        for (int j = 0; j < 8; ++j) {
          p0[j] = f2b(b2f(p0[j]) * fixrow[k0 + scg + j]);
          p1[j] = f2b(b2f(p1[j]) * fixrow[k0 + scg + 8 + j]);
        }
      }
      *(short8*)&sB[srow][scg] = v0;
      *(short8*)&sB[srow][scg + 8] = v1;
    }
    __syncthreads();
    short8 af[4], bf[4];
    #pragma unroll
    for (int i = 0; i < 4; ++i)
      af[i] = *(const short8*)&sA[wm + i * 16 + lr][lq * 8];
    #pragma unroll
    for (int j = 0; j < 4; ++j)
      bf[j] = *(const short8*)&sB[wn + j * 16 + lr][lq * 8];
    #pragma unroll
    for (int i = 0; i < 4; ++i)
      #pragma unroll
      for (int j = 0; j < 4; ++j)
        acc[i][j] = __builtin_amdgcn_mfma_f32_16x16x32_bf16(af[i], bf[j], acc[i][j], 0, 0, 0);
    __syncthreads();
  }

  #pragma unroll
  for (int i = 0; i < 4; ++i) {
    #pragma unroll
    for (int j = 0; j < 4; ++j) {
      int col = n0 + wn + j * 16 + lr;
      #pragma unroll
      for (int r = 0; r < 4; ++r) {
        int row = m0 + wm + i * 16 + lq * 4 + r;
        float v = acc[i][j][r];
        if (MODE == 0) {
          v += bias[col];
          outB[(long long)row * N + col] = f2b(v);
        } else if (MODE == 3) {
          outB[(long long)row * N + col] = f2b(v);
        } else {
          out_b[(long long)row * N + col] = v;
        }
      }
    }
  }
}

extern "C" void kernel_launch(void* const* d_in, const int* in_sizes, int n_in,
                              void* d_out, int out_size, void* d_ws, size_t ws_size,
                              hipStream_t stream) {
  const float* main_feat  = (const float*)d_in[0];
  const float* other_feat = (const float*)d_in[1];
  const float* fix_feat   = (const float*)d_in[2];
  const int*   mask       = (const int*)d_in[3];
  const float* Wq         = (const float*)d_in[4];
  const float* bq         = (const float*)d_in[5];
  const float* Wk         = (const float*)d_in[6];
  const float* bk         = (const float*)d_in[7];
  float* out = (float*)d_out;

  char* ws = (char*)d_ws;
  const size_t OFF_MAINB  = 0;          // 2 MiB (mainB, otherB contiguous)
  const size_t OFF_OTHERB = 2097152;    // 2 MiB
  const size_t OFF_WQB    = 4194304;    // 512 KiB
  const size_t OFF_WKB    = 4718592;    // 512 KiB
  const size_t OFF_QB     = 5242880;    // 2 MiB (QB, KB contiguous)
  const size_t OFF_KB     = 7340032;    // 2 MiB
  const size_t OFF_OTB    = 9437184;    // 2 MiB (fallback only)
  const size_t OFF_P      = 11534336;   // 8 MiB (P bf16 [2048][2048])
  const size_t OFF_S      = 19922944;   // 8 MiB used (S bf16 [2048][2048])
  const size_t OFF_SCALED = 36700160;   // 64 MiB (scaled bf16 [32][512][2048])
  const size_t NEED_SCALED = OFF_SCALED + (size_t)BATCH_ * 512 * 2048 * 2;

  u16* mainB  = (u16*)(ws + OFF_MAINB);
  u16* otherB = (u16*)(ws + OFF_OTHERB);
  u16* WqB    = (u16*)(ws + OFF_WQB);
  u16* WkB    = (u16*)(ws + OFF_WKB);
  u16* QB     = (u16*)(ws + OFF_QB);
  u16* KB     = (u16*)(ws + OFF_KB);
  u16* oTB    = (u16*)(ws + OFF_OTB);
  u16* P      = (u16*)(ws + OFF_P);
  u16* S      = (u16*)(ws + OFF_S);
  u16* scaled = (u16*)(ws + OFF_SCALED);
  bool use_scaled = (ws_size >= NEED_SCALED);

  // 1) bf16 conversions (two dual launches)
  cvt_bf16_dual<<<2048, 256, 0, stream>>>(main_feat, mainB, 2048 * 512,
                                          other_feat, otherB, 2048 * 512);
  cvt_bf16_dual<<<512, 256, 0, stream>>>(Wq, WqB, 512 * 512,
                                         Wk, WkB, 512 * 512);

  if (use_scaled) {
    // 2) fused transpose+scale: scaled[b][k][o] (no oTB round-trip)
    transpose_scale<<<dim3(16, 64), 256, 0, stream>>>(other_feat, fix_feat, scaled);
    // 3) fused Q|K projection: M=4096 (rows 0..2047 -> Wq/bq, 2048.. -> Wk/bk)
    gemm_lds<0><<<dim3(4, 32), 256, 0, stream>>>(mainB, WqB, bq, WkB, bk,
        nullptr, QB, 4096, 512, 512);
    // 4) S = Q @ K^T (bf16 out, unscaled; softmax applies 1/sqrt(512))
    gemm_lds<3><<<dim3(16, 16), 256, 0, stream>>>(QB, KB, nullptr, nullptr, nullptr,
        nullptr, S, 2048, 2048, 512);
    // 5) masked softmax -> P bf16
    softmax_mask<<<2048, 256, 0, stream>>>(S, mask, P, 2048);
    // 6) ring-4 pipelined GEMM (R7): out[b][m][k] via col scatter
    gemm_ring<<<dim3(8, 64), 512, 0, stream>>>(P, scaled, out, 2048, 16384, 2048);
  } else {
    // fallback: no 64MB scaled buffer
    transpose_cvt<<<dim3(16, 64), 256, 0, stream>>>(other_feat, oTB, 2048, 512);
    gemm_bt<0><<<dim3(4, 16, 1), 256, 0, stream>>>(mainB, WqB, bq, nullptr,
        nullptr, QB, 2048, 512, 512, 0, 0);
    gemm_bt<0><<<dim3(4, 16, 1), 256, 0, stream>>>(otherB, WkB, bk, nullptr,
        nullptr, KB, 2048, 512, 512, 0, 0);
    gemm_bt<3><<<dim3(16, 16, 1), 256, 0, stream>>>(QB, KB, nullptr, nullptr,
        nullptr, S, 2048, 2048, 512, 0, 0);
    softmax_mask<<<2048, 256, 0, stream>>>(S, mask, P, 2048);
    gemm_bt<2><<<dim3(4, 16, BATCH_), 256, 0, stream>>>(P, oTB, nullptr, fix_feat,
        out, nullptr, 2048, 512, 2048, 1048576LL, 0);
  }
}